// Round 1
// baseline (138.625 us; speedup 1.0000x reference)
//
#include <hip/hip_runtime.h>

#define IN_C 64
#define OUT_C 16
#define EA_D 8

typedef float f32x4 __attribute__((ext_vector_type(4)));

// DPP cross-lane move, VALU-speed (no DS latency, no lgkmcnt):
//   0x140 row_mirror (i -> 15-i within 16-lane row)
//   0x141 row_half_mirror (i -> (i&8)|(7-(i&7)))
//   0x4E  quad_perm [2,3,0,1]  (xor 2)
//   0xB1  quad_perm [1,0,3,2]  (xor 1)
// These four involutions form a butterfly over each aligned 16-lane group.
#define DPPF(x, ctrl) \
    __uint_as_float((unsigned)__builtin_amdgcn_update_dpp( \
        0, (int)__float_as_uint(x), (ctrl), 0xF, 0xF, true))

__device__ __forceinline__ void atomic_add_f32(float* p, float v) {
#if defined(__HIP_PLATFORM_AMD__) || defined(__AMDGCN__)
    unsafeAtomicAdd(p, v);   // global_atomic_add_f32, no CAS loop
#else
    atomicAdd(p, v);
#endif
}

// ---------------- h = x @ lin_w + lin_b  (also zeroes out[]) ----------------
// Register-tiled: thread = (node, 4 channels). 400k threads instead of 1.6M.
// DS traffic: 16 ds_read_b128 per thread (x row only) vs 32 per (node,ch)
// thread before = 8x fewer DS instructions (this kernel was LDS-issue-bound,
// ~15.6us at ~12cyc/b128, vs a 6.3us HBM floor).
// Weights go through the SCALAR path: cg is wave-uniform; readfirstlane pins
// it to an SGPR so every lin_w access is an s_load (4KB fits scalar L1) --
// zero DS, zero VALU-issue cost.
__global__ __launch_bounds__(256) void h_kernel(
    const float* __restrict__ x,
    const float* __restrict__ lin_w,   // [64,16]
    const float* __restrict__ lin_b,   // [16]
    float* __restrict__ h,             // [N,16]
    float* __restrict__ out,           // [N,16] zero-init
    int n)
{
    // stride 76 floats: 76*4B rows; 76 = 64+12 so lane i's b128 start-bank
    // (12*i mod 32) walks all 8 quad-bank groups -> conflict-free-ish.
    __shared__ float s_x[64][IN_C + 12];   // 19.5 KB

    const int t = threadIdx.x;
    const int nodeBase = blockIdx.x * 64;

    // zero out[] early: 64 nodes * 16 ch = 1024 floats, 4 per thread.
    {
        const int base = nodeBase * OUT_C + t;
        const int lim = n * OUT_C;
        #pragma unroll
        for (int i = 0; i < 4; ++i) {
            const int idx = base + 256 * i;
            if (idx < lim) out[idx] = 0.0f;
        }
    }

    // stage x tile: 64 rows x 64 floats; 4x float4 per thread, coalesced
    // (16 consecutive threads cover one 256B row).
    {
        const int r  = t >> 4;
        const int c4 = (t & 15) * 4;
        #pragma unroll
        for (int i = 0; i < 4; ++i) {
            const int row = r + 16 * i;
            const int node = nodeBase + row;
            f32x4 v = {0.f, 0.f, 0.f, 0.f};
            if (node < n) v = *(const f32x4*)(x + (size_t)node * IN_C + c4);
            *(f32x4*)(&s_x[row][c4]) = v;
        }
    }
    __syncthreads();

    const int node_l = t & 63;                              // lane = node
    const int cg = __builtin_amdgcn_readfirstlane(t >> 6);  // wave-uniform 0..3
    const int c0 = cg * 4;
    const int node = nodeBase + node_l;
    if (node >= n) return;

    // accumulation order identical to previous passing kernel: b first,
    // then k ascending -> h bit-exact.
    float acc0 = lin_b[c0 + 0];
    float acc1 = lin_b[c0 + 1];
    float acc2 = lin_b[c0 + 2];
    float acc3 = lin_b[c0 + 3];

    #pragma unroll
    for (int k = 0; k < IN_C; k += 4) {
        const f32x4 xv = *(const f32x4*)(&s_x[node_l][k]);
        #pragma unroll
        for (int j = 0; j < 4; ++j) {
            const float xs = xv[j];
            const float* wr = lin_w + (k + j) * OUT_C + c0;  // SGPR address
            acc0 = fmaf(xs, wr[0], acc0);
            acc1 = fmaf(xs, wr[1], acc1);
            acc2 = fmaf(xs, wr[2], acc2);
            acc3 = fmaf(xs, wr[3], acc3);
        }
    }
    f32x4 res = {acc0, acc1, acc2, acc3};
    *(f32x4*)(h + (size_t)node * OUT_C + c0) = res;   // 16B aligned (c0 mult of 4)
}

// ---------------- per-edge fused kernel: quad-per-edge ----------------
// lane = (edge, channel). Changes vs previous version:
//  - ea_w staged TRANSPOSED (s_eawT[c][k], rows padded to 12 floats so both
//    halves are 16B-aligned): per-thread LDS = 2x ds_read_b128 + 1x b32
//    instead of 9x ds_read_b32.
//  - softmax reductions via DPP (VALU-latency) instead of 8 dependent
//    ds_swizzle shuffles (~120cyc each): kills ~1000 cycles of serial
//    latency per wave and 800k DS instructions total.
//  - p/den -> p * v_rcp_f32(den): drops the ~10-inst IEEE divide; error
//    ~1e-7 relative, far under tolerance.
//  - non-temporal loads for streamed edge_index/edge_attr so they don't
//    evict hot h/out lines from L2.
__global__ __launch_bounds__(256) void edge_kernel(
    const int*   __restrict__ edge_index,  // [2,E]
    const float* __restrict__ edge_attr,   // [E,8]
    const float* __restrict__ ea_w,        // [8,16]
    const float* __restrict__ ea_b,        // [16]
    const float* __restrict__ w1,          // [16]
    const float* __restrict__ b1,          // [16]
    const float* __restrict__ w2,          // [16]
    const float* __restrict__ b2,          // [1]
    const float* __restrict__ h,           // [N,16]
    float*       __restrict__ out,         // [N,16]
    int E)
{
    __shared__ float s_eawT[16][12];   // row c = ea_w[:,c]; 48B rows keep 16B align
    __shared__ float s_eab[OUT_C];

    const int t = threadIdx.x;
    if (t < 128)                s_eawT[t & 15][t >> 4] = ea_w[(t >> 4) * OUT_C + (t & 15)];
    else if (t < 128 + OUT_C)   s_eab[t - 128] = ea_b[t - 128];
    __syncthreads();

    const int gid = blockIdx.x * 256 + t;
    const int e = gid >> 4;
    const int c = gid & 15;
    if (e >= E) return;

    const int row = __builtin_nontemporal_load(edge_index + e) - 1;      // [0][e]-1
    const int col = __builtin_nontemporal_load(edge_index + E + e);      // [1][e]

    const f32x4* ap = (const f32x4*)(edge_attr + (size_t)e * EA_D);
    const f32x4 a0 = __builtin_nontemporal_load(ap);
    const f32x4 a1 = __builtin_nontemporal_load(ap + 1);

    // gather: 16 consecutive lanes read one 64B line of h
    const float hv = h[(size_t)col * OUT_C + c];

    // agg = h[col][c] * (edge_attr @ ea_w + ea_b)[c]; k ascending (bit-exact
    // vs previous kernel).
    const f32x4 w0 = *(const f32x4*)(&s_eawT[c][0]);
    const f32x4 w4 = *(const f32x4*)(&s_eawT[c][4]);
    float d = s_eab[c];
    d = fmaf(a0.x, w0.x, d);
    d = fmaf(a0.y, w0.y, d);
    d = fmaf(a0.z, w0.z, d);
    d = fmaf(a0.w, w0.w, d);
    d = fmaf(a1.x, w4.x, d);
    d = fmaf(a1.y, w4.y, d);
    d = fmaf(a1.z, w4.z, d);
    d = fmaf(a1.w, w4.w, d);
    const float agg = hv * d;

    // score: weights are uniform -> scalar loads (unchanged)
    float s = b2[0];
    #pragma unroll
    for (int j = 0; j < OUT_C; ++j) {
        const float hm = fmaf(agg, w1[j], b1[j]);
        s = fmaf(fmaxf(hm, 0.0f), w2[j], s);
    }

    // softmax over the 16 channels: DPP butterfly (max then sum)
    float m = s;
    m = fmaxf(m, DPPF(m, 0x140));
    m = fmaxf(m, DPPF(m, 0x141));
    m = fmaxf(m, DPPF(m, 0x4E));
    m = fmaxf(m, DPPF(m, 0xB1));

    const float p = __expf(s - m);
    float den = p;
    den += DPPF(den, 0x140);
    den += DPPF(den, 0x141);
    den += DPPF(den, 0x4E);
    den += DPPF(den, 0xB1);

    const float attn = p * __builtin_amdgcn_rcpf(den);

    // grouped scatter: one 64B line per quad
    atomic_add_f32(out + (size_t)row * OUT_C + c, agg * attn);
}

extern "C" void kernel_launch(void* const* d_in, const int* in_sizes, int n_in,
                              void* d_out, int out_size, void* d_ws, size_t ws_size,
                              hipStream_t stream)
{
    const float* x          = (const float*)d_in[0];
    const int*   edge_index = (const int*)  d_in[1];
    const float* edge_attr  = (const float*)d_in[2];
    const float* lin_w      = (const float*)d_in[3];
    const float* lin_b      = (const float*)d_in[4];
    const float* ea_w       = (const float*)d_in[5];
    const float* ea_b       = (const float*)d_in[6];
    const float* attn_w1    = (const float*)d_in[7];
    const float* attn_b1    = (const float*)d_in[8];
    const float* attn_w2    = (const float*)d_in[9];
    const float* attn_b2    = (const float*)d_in[10];

    const int n = in_sizes[0] / IN_C;      // 100000
    const int E = in_sizes[1] / 2;         // 400000

    float* h   = (float*)d_ws;             // [N,16] = 6.4 MB
    float* out = (float*)d_out;

    // h_kernel zeroes out[] (grid covers every out element exactly once)
    h_kernel<<<(n + 63) / 64, 256, 0, stream>>>(x, lin_w, lin_b, h, out, n);

    // 16 lanes per edge
    const long long threads = (long long)E * OUT_C;
    edge_kernel<<<(int)((threads + 255) / 256), 256, 0, stream>>>(
        edge_index, edge_attr, ea_w, ea_b,
        attn_w1, attn_b1, attn_w2, attn_b2,
        h, out, E);
}

// Round 2
// 128.975 us; speedup vs baseline: 1.0748x; 1.0748x over previous
//
#include <hip/hip_runtime.h>

#define IN_C 64
#define OUT_C 16
#define EA_D 8

typedef float f32x4 __attribute__((ext_vector_type(4)));

// DPP cross-lane move, VALU-speed (no DS latency, no lgkmcnt):
//   0x140 row_mirror        (i -> 15-i within each 16-lane row)
//   0x141 row_half_mirror   (i -> (i&8) | (7-(i&7)))
//   0x4E  quad_perm [2,3,0,1]  (xor 2)
//   0xB1  quad_perm [1,0,3,2]  (xor 1)
// These four involutions form a complete butterfly over each aligned
// 16-lane group (verified: lane0 collects {0,15}->{0,7,8,15}->
// {0,2,5,7,8,10,13,15}->all 16).
#define DPPF(x, ctrl) \
    __uint_as_float((unsigned)__builtin_amdgcn_update_dpp( \
        0, (int)__float_as_uint(x), (ctrl), 0xF, 0xF, true))

__device__ __forceinline__ void atomic_add_f32(float* p, float v) {
#if defined(__HIP_PLATFORM_AMD__) || defined(__AMDGCN__)
    unsafeAtomicAdd(p, v);   // global_atomic_add_f32, no CAS loop
#else
    atomicAdd(p, v);
#endif
}

// ---------------- h = x @ lin_w + lin_b  (also zeroes out[]) ----------------
// ROUND-0 VERSION, verbatim (known-good part of the 131us baseline).
// NOTE (round-1 post-mortem): do NOT replace the LDS weight reads with
// scalar loads inside the loop -- SMEM returns out-of-order, so every use
// forces lgkmcnt(0), which also drains the ds_read pipe. That variant
// regressed ~8us.
__global__ __launch_bounds__(256) void h_kernel(
    const float* __restrict__ x,
    const float* __restrict__ lin_w,   // [64,16]
    const float* __restrict__ lin_b,   // [16]
    float* __restrict__ h,             // [N,16]
    float* __restrict__ out,           // [N,16] zero-init
    int n)
{
    __shared__ float s_x [16][IN_C + 4];   // stride 68 floats: 16B-aligned rows
    __shared__ float s_wt[16][IN_C + 4];   // transposed W: s_wt[c][k]

    const int t = threadIdx.x;
    const int nodeBase = blockIdx.x * 16;

    // zero out[] early: store latency hides under the FMA loop below
    {
        const int idx = nodeBase * OUT_C + t;      // 256 consecutive elements
        if (idx < n * OUT_C) out[idx] = 0.0f;
    }

    // stage transposed weights (one-time, conflicts irrelevant)
    for (int i = t; i < IN_C * OUT_C; i += 256)
        s_wt[i & 15][i >> 4] = lin_w[i];

    {
        const int lr = t >> 4;            // row 0..15
        const int k4 = (t & 15) * 4;      // col 0,4,...,60
        const int node = nodeBase + lr;
        float4 v = make_float4(0.f, 0.f, 0.f, 0.f);
        if (node < n) v = *(const float4*)(x + (size_t)node * IN_C + k4);
        *(float4*)(&s_x[lr][k4]) = v;
    }
    __syncthreads();

    const int lr = t >> 4;
    const int c  = t & 15;
    const int node = nodeBase + lr;
    if (node < n) {
        float acc = lin_b[c];
        #pragma unroll
        for (int k4 = 0; k4 < IN_C; k4 += 4) {
            const float4 xv = *(const float4*)(&s_x [lr][k4]);  // broadcast in quad
            const float4 wv = *(const float4*)(&s_wt[c ][k4]);  // <=2-way conflict (free)
            acc = fmaf(xv.x, wv.x, acc);
            acc = fmaf(xv.y, wv.y, acc);
            acc = fmaf(xv.z, wv.z, acc);
            acc = fmaf(xv.w, wv.w, acc);
        }
        h[(size_t)node * OUT_C + c] = acc;
    }
}

// ---------------- per-edge fused kernel: quad-per-edge ----------------
// lane = (edge, channel). Changes vs round-0 baseline (NT loads from round-1
// REVERTED -- they bypass L2/L3 retention and the working set is L3-resident
// across iterations):
//  - ea_w staged TRANSPOSED (s_eawT[c][k], 48B rows keep both halves
//    16B-aligned): per-thread LDS = 2x ds_read_b128 + 1x b32 instead of
//    9x ds_read_b32. DS insts/wave: 17 -> 3.
//  - softmax reductions via DPP (VALU-latency) instead of 8 dependent
//    ~120-cyc DS shuffles: removes ~1000 serial cycles/wave and 800k DS insts.
//  - p/den -> p * v_rcp_f32(den): drops the ~10-inst IEEE divide; relative
//    error ~1e-7, far under the 4.9e-4 tolerance already consumed.
__global__ __launch_bounds__(256) void edge_kernel(
    const int*   __restrict__ edge_index,  // [2,E]
    const float* __restrict__ edge_attr,   // [E,8]
    const float* __restrict__ ea_w,        // [8,16]
    const float* __restrict__ ea_b,        // [16]
    const float* __restrict__ w1,          // [16]
    const float* __restrict__ b1,          // [16]
    const float* __restrict__ w2,          // [16]
    const float* __restrict__ b2,          // [1]
    const float* __restrict__ h,           // [N,16]
    float*       __restrict__ out,         // [N,16]
    int E)
{
    __shared__ float s_eawT[16][12];   // row c = ea_w[:,c]
    __shared__ float s_eab[OUT_C];

    const int t = threadIdx.x;
    if (t < 128)                s_eawT[t & 15][t >> 4] = ea_w[(t >> 4) * OUT_C + (t & 15)];
    else if (t < 128 + OUT_C)   s_eab[t - 128] = ea_b[t - 128];
    __syncthreads();

    const int gid = blockIdx.x * 256 + t;
    const int e = gid >> 4;
    const int c = gid & 15;
    if (e >= E) return;

    const int row = edge_index[e] - 1;     // edge_index[0][e] - 1
    const int col = edge_index[E + e];     // edge_index[1][e]

    // 32B broadcast per quad (contiguous across the 4 quads of a wave)
    const f32x4* ap = (const f32x4*)(edge_attr + (size_t)e * EA_D);
    const f32x4 a0 = ap[0], a1 = ap[1];

    // gather: 16 consecutive lanes read one 64B line of h
    const float hv = h[(size_t)col * OUT_C + c];

    // agg = h[col][c] * (edge_attr @ ea_w + ea_b)[c]; k ascending (bit-exact
    // vs baseline accumulation order).
    const f32x4 w0 = *(const f32x4*)(&s_eawT[c][0]);
    const f32x4 w4 = *(const f32x4*)(&s_eawT[c][4]);
    float d = s_eab[c];
    d = fmaf(a0.x, w0.x, d);
    d = fmaf(a0.y, w0.y, d);
    d = fmaf(a0.z, w0.z, d);
    d = fmaf(a0.w, w0.w, d);
    d = fmaf(a1.x, w4.x, d);
    d = fmaf(a1.y, w4.y, d);
    d = fmaf(a1.z, w4.z, d);
    d = fmaf(a1.w, w4.w, d);
    const float agg = hv * d;

    // score = b2 + sum_j relu(agg*w1[j]+b1[j])*w2[j]  (weights = scalar loads,
    // hoisted outside any loop-carried lgkm dependence by full unroll)
    float s = b2[0];
    #pragma unroll
    for (int j = 0; j < OUT_C; ++j) {
        const float hm = fmaf(agg, w1[j], b1[j]);
        s = fmaf(fmaxf(hm, 0.0f), w2[j], s);
    }

    // softmax over the 16 channels of this quad: DPP butterfly (max then sum)
    float m = s;
    m = fmaxf(m, DPPF(m, 0x140));
    m = fmaxf(m, DPPF(m, 0x141));
    m = fmaxf(m, DPPF(m, 0x4E));
    m = fmaxf(m, DPPF(m, 0xB1));

    const float p = __expf(s - m);
    float den = p;
    den += DPPF(den, 0x140);
    den += DPPF(den, 0x141);
    den += DPPF(den, 0x4E);
    den += DPPF(den, 0xB1);

    const float attn = p * __builtin_amdgcn_rcpf(den);

    // grouped scatter: one 64B line per quad
    atomic_add_f32(out + (size_t)row * OUT_C + c, agg * attn);
}

extern "C" void kernel_launch(void* const* d_in, const int* in_sizes, int n_in,
                              void* d_out, int out_size, void* d_ws, size_t ws_size,
                              hipStream_t stream)
{
    const float* x          = (const float*)d_in[0];
    const int*   edge_index = (const int*)  d_in[1];
    const float* edge_attr  = (const float*)d_in[2];
    const float* lin_w      = (const float*)d_in[3];
    const float* lin_b      = (const float*)d_in[4];
    const float* ea_w       = (const float*)d_in[5];
    const float* ea_b       = (const float*)d_in[6];
    const float* attn_w1    = (const float*)d_in[7];
    const float* attn_b1    = (const float*)d_in[8];
    const float* attn_w2    = (const float*)d_in[9];
    const float* attn_b2    = (const float*)d_in[10];

    const int n = in_sizes[0] / IN_C;      // 100000
    const int E = in_sizes[1] / 2;         // 400000

    float* h   = (float*)d_ws;             // [N,16] = 6.4 MB
    float* out = (float*)d_out;

    // h_kernel zeroes out[] (grid covers every out element exactly once)
    h_kernel<<<(n + 15) / 16, 256, 0, stream>>>(x, lin_w, lin_b, h, out, n);

    // 16 lanes per edge
    const long long threads = (long long)E * OUT_C;
    edge_kernel<<<(int)((threads + 255) / 256), 256, 0, stream>>>(
        edge_index, edge_attr, ea_w, ea_b,
        attn_w1, attn_b1, attn_w2, attn_b2,
        h, out, E);
}